// Round 7
// baseline (781.525 us; speedup 1.0000x reference)
//
#include <hip/hip_runtime.h>
#include <stdint.h>

#define E 128
#define W 64
#define C 1024
#define S 8
#define NBUCK 4096

typedef unsigned long long u64;
typedef unsigned int u32;

__device__ __forceinline__ float sigm(float x) { return 1.0f / (1.0f + expf(-x)); }

// ---------------------------------------------------------------------------
// kFeat: per-beam LSTM + MLP chain. grid = 64 x 256.
//   Consumes staged xinb/cpb/curid (from previous step's kSP top phase).
//   step 0: zero state, cur = start_ent, also zeroes handshake flags.
// ---------------------------------------------------------------------------
__global__ __launch_bounds__(256) void kFeat(
    int step,
    const float* __restrict__ ent_emb, const float* __restrict__ relation,
    const float* __restrict__ W1, const float* __restrict__ b1,
    const float* __restrict__ W2, const float* __restrict__ b2,
    const float* __restrict__ lstm_k, const float* __restrict__ lstm_r,
    const float* __restrict__ lstm_b,
    const int* __restrict__ start_ent,
    const float* __restrict__ xinb,   // [W][384] staged [rel, ent, h_par]
    const float* __restrict__ cpb,    // [W][128] staged c_parent
    const int* __restrict__ curid,    // [W]
    float* __restrict__ Hst, float* __restrict__ Cst,   // [W][E]
    float* __restrict__ featb,                           // [W][256]
    int* __restrict__ scnt, int* __restrict__ gcnt)
{
  const int w = blockIdx.x, t = threadIdx.x;
  __shared__ __align__(16) float xin[384];
  __shared__ __align__(16) float z[512];
  __shared__ __align__(16) float hnew[128];
  __shared__ __align__(16) float xcat[384];
  __shared__ __align__(16) float hmid[384];

  int cur;
  if (step == 0) {
    if (t == 0) { scnt[w] = 0; if (w == 0) *gcnt = 0; }
    if (t < 128) {
      hnew[t] = 0.f;
      Hst[w * E + t] = 0.f;
      Cst[w * E + t] = 0.f;
    }
    cur = start_ent[w];
  } else {
    cur = curid[w];
    for (int i = t; i < 384; i += 256) xin[i] = xinb[(size_t)w * 384 + i];
    __syncthreads();
    {
      const int j = t, j2 = t + 256;
      const float4* xv4 = (const float4*)xin;
      float a0 = 0.f, a1 = 0.f, a2 = 0.f, a3 = 0.f;
      float d0 = 0.f, d1 = 0.f, d2 = 0.f, d3 = 0.f;
#pragma unroll 4
      for (int k4 = 0; k4 < 64; ++k4) {
        const float4 xv = xv4[k4];
        const float* K0 = lstm_k + (size_t)(k4 * 4) * 512;
        a0 += xv.x * K0[j];  a1 += xv.y * K0[512 + j];
        a2 += xv.z * K0[1024 + j]; a3 += xv.w * K0[1536 + j];
        d0 += xv.x * K0[j2]; d1 += xv.y * K0[512 + j2];
        d2 += xv.z * K0[1024 + j2]; d3 += xv.w * K0[1536 + j2];
      }
#pragma unroll 4
      for (int k4 = 0; k4 < 32; ++k4) {
        const float4 xv = xv4[64 + k4];
        const float* R0 = lstm_r + (size_t)(k4 * 4) * 512;
        a0 += xv.x * R0[j];  a1 += xv.y * R0[512 + j];
        a2 += xv.z * R0[1024 + j]; a3 += xv.w * R0[1536 + j];
        d0 += xv.x * R0[j2]; d1 += xv.y * R0[512 + j2];
        d2 += xv.z * R0[1024 + j2]; d3 += xv.w * R0[1536 + j2];
      }
      z[j]  = lstm_b[j]  + ((a0 + a1) + (a2 + a3));
      z[j2] = lstm_b[j2] + ((d0 + d1) + (d2 + d3));
    }
    __syncthreads();
    if (t < 128) {
      const float zi = z[t], zf = z[128 + t], zg = z[256 + t], zo = z[384 + t];
      const float cp = cpb[(size_t)w * E + t];
      const float cn = sigm(zf) * cp + sigm(zi) * tanhf(zg);
      const float hn = sigm(zo) * tanhf(cn);
      hnew[t] = hn;
      Hst[w * E + t] = hn;
      Cst[w * E + t] = cn;
    }
  }
  __syncthreads();

  // xcat = [ent_emb[cur], hnew, relation]
  for (int i = t; i < 384; i += 256) {
    float v;
    if (i < 128) v = ent_emb[(size_t)cur * E + i];
    else if (i < 256) v = hnew[i - 128];
    else v = relation[i - 256];
    xcat[i] = v;
  }
  __syncthreads();

  // MLP1: hmid = relu(xcat @ W1 + b1)   (384 outputs)
  {
    const float4* xv4 = (const float4*)xcat;
    for (int j = t; j < 384; j += 256) {
      float a0 = 0.f, a1 = 0.f, a2 = 0.f, a3 = 0.f;
#pragma unroll 4
      for (int k4 = 0; k4 < 96; ++k4) {
        const float4 xv = xv4[k4];
        const float* Wp = W1 + (size_t)(k4 * 4) * 384 + j;
        a0 += xv.x * Wp[0];   a1 += xv.y * Wp[384];
        a2 += xv.z * Wp[768]; a3 += xv.w * Wp[1152];
      }
      hmid[j] = fmaxf(b1[j] + ((a0 + a1) + (a2 + a3)), 0.f);
    }
  }
  __syncthreads();

  // MLP2: feat = relu(hmid @ W2 + b2)   (256 outputs)
  {
    const float4* xv4 = (const float4*)hmid;
    const int j = t;
    float a0 = 0.f, a1 = 0.f, a2 = 0.f, a3 = 0.f;
#pragma unroll 4
    for (int k4 = 0; k4 < 96; ++k4) {
      const float4 xv = xv4[k4];
      const float* Wp = W2 + (size_t)(k4 * 4) * 256 + j;
      a0 += xv.x * Wp[0];   a1 += xv.y * Wp[256];
      a2 += xv.z * Wp[512]; a3 += xv.w * Wp[768];
    }
    featb[(size_t)w * 256 + j] = fmaxf(b2[j] + ((a0 + a1) + (a2 + a3)), 0.f);
  }
}

// ---------------------------------------------------------------------------
// kSP: fused score + softmax/rowtop + global top + stage. grid = 512 x 512.
//   All 512 blocks co-resident (<=128 VGPR via launch_bounds, ~33KB LDS).
//   Handshakes: monotone agent-scope counters (scnt[w], gcnt).
// ---------------------------------------------------------------------------
__global__ __launch_bounds__(512, 4) void kSP(
    int step, int last,
    const float* __restrict__ ent_emb, const float* __restrict__ rel_emb,
    const float* __restrict__ relation,
    const int* __restrict__ cand_rel_ids, const int* __restrict__ cand_ent_ids,
    const float* __restrict__ featb, float* __restrict__ scoresb,
    float* __restrict__ out, u64* __restrict__ rowtop,
    const float* __restrict__ Hst, const float* __restrict__ Cst,
    float* __restrict__ xinb, float* __restrict__ cpb, int* __restrict__ curid,
    int* __restrict__ scnt, int* __restrict__ gcnt)
{
  const int b = blockIdx.x, t = threadIdx.x;
  const int w = b >> 3, c0 = (b & 7) << 7;
  __shared__ __align__(16) unsigned char arena[32768];
  float* featl = (float*)arena;                 // 1 KB   (score phase)
  int* srid = (int*)(arena + 1024);             // 0.5 KB
  int* seid = (int*)(arena + 1536);             // 0.5 KB
  u32* hist = (u32*)arena;                      // 16 KB  (prob/top phases)
  u64* coll = (u64*)arena;                      // up to 32 KB (after threshold)
  __shared__ float sred[8];
  __shared__ float s_scal[2];
  __shared__ int s_cnt, s_B;
  __shared__ int s_par[64], s_rid[64], s_eid[64];

  // ================= score =================
  {
    const size_t idbase = (size_t)step * W * C + (size_t)w * C + c0;
    if (t < 256) featl[t] = featb[(size_t)w * 256 + t];
    else if (t < 384) srid[t - 256] = cand_rel_ids[idbase + (t - 256)];
    else seid[t - 384] = cand_ent_ids[idbase + (t - 384)];
    __syncthreads();
    const int cl = t >> 2, j = t & 3;
    const float4* rp = (const float4*)(rel_emb + (size_t)srid[cl] * E);
    const float4* ep = (const float4*)(ent_emb + (size_t)seid[cl] * E);
    const float4* f4 = (const float4*)featl;
    float ax = 0.f, ay = 0.f, az = 0.f, aw = 0.f;
#pragma unroll
    for (int i = 0; i < 8; ++i) {
      const float4 r = rp[j + 4 * i], f = f4[j + 4 * i];
      ax += r.x * f.x; ay += r.y * f.y; az += r.z * f.z; aw += r.w * f.w;
    }
#pragma unroll
    for (int i = 0; i < 8; ++i) {
      const float4 e = ep[j + 4 * i], f = f4[32 + j + 4 * i];
      ax += e.x * f.x; ay += e.y * f.y; az += e.z * f.z; aw += e.w * f.w;
    }
    float acc = (ax + ay) + (az + aw);
    acc += __shfl_xor(acc, 1, 64);
    acc += __shfl_xor(acc, 2, 64);
    if (j == 0)
      __hip_atomic_store(&scoresb[(size_t)w * C + c0 + cl], acc,
                         __ATOMIC_RELAXED, __HIP_MEMORY_SCOPE_AGENT);
  }
  __syncthreads();
  if (t == 0)
    __hip_atomic_fetch_add(&scnt[w], 1, __ATOMIC_RELEASE, __HIP_MEMORY_SCOPE_AGENT);
  if ((b & 7) != 0) return;

  // ================= prob (slice-0 block per beam) =================
  if (t == 0) {
    const int target = 8 * (step + 1);
    while (__hip_atomic_load(&scnt[w], __ATOMIC_RELAXED, __HIP_MEMORY_SCOPE_AGENT) < target)
      __builtin_amdgcn_s_sleep(8);
    __builtin_amdgcn_fence(__ATOMIC_ACQUIRE, "agent");
  }
  __syncthreads();

  const float sc0 = __hip_atomic_load(&scoresb[(size_t)w * C + t],
                                      __ATOMIC_RELAXED, __HIP_MEMORY_SCOPE_AGENT);
  const float sc1 = __hip_atomic_load(&scoresb[(size_t)w * C + 512 + t],
                                      __ATOMIC_RELAXED, __HIP_MEMORY_SCOPE_AGENT);
  float v = fmaxf(sc0, sc1);
#pragma unroll
  for (int d = 32; d; d >>= 1) v = fmaxf(v, __shfl_xor(v, d, 64));
  if ((t & 63) == 0) sred[t >> 6] = v;
  __syncthreads();
  if (t == 0) {
    float mm = sred[0];
#pragma unroll
    for (int i = 1; i < 8; ++i) mm = fmaxf(mm, sred[i]);
    s_scal[0] = mm;
  }
  __syncthreads();
  const float m = s_scal[0];
  const float p0 = expf(sc0 - m), p1 = expf(sc1 - m);
  v = p0 + p1;
#pragma unroll
  for (int d = 32; d; d >>= 1) v += __shfl_xor(v, d, 64);
  if ((t & 63) == 0) sred[t >> 6] = v;
  __syncthreads();
  if (t == 0) {
    float ss = sred[0];
#pragma unroll
    for (int i = 1; i < 8; ++i) ss += sred[i];
    s_scal[1] = 1.f / ss;
  }
  __syncthreads();
  const float inv = s_scal[1];
  const float prob0 = p0 * inv, prob1 = p1 * inv;
  out[(size_t)step * W * C + (size_t)w * C + t] = prob0;
  out[(size_t)step * W * C + (size_t)w * C + 512 + t] = prob1;
  if (last) return;

  // per-row top-64 via 12-bit histogram
  for (int i = t; i < NBUCK; i += 512) hist[i] = 0;
  if (t == 0) s_cnt = 0;
  __syncthreads();
  const u32 mono0 = __float_as_uint(prob0) | 0x80000000u;
  const u32 mono1 = __float_as_uint(prob1) | 0x80000000u;
  const u64 k0 = ((u64)mono0 << 32) | (u32)~(u32)(w * C + t);
  const u64 k1 = ((u64)mono1 << 32) | (u32)~(u32)(w * C + 512 + t);
  atomicAdd(&hist[(mono0 >> 19) & 0xFFFu], 1u);
  atomicAdd(&hist[(mono1 >> 19) & 0xFFFu], 1u);
  __syncthreads();
  for (int off = 1; off < NBUCK; off <<= 1) {
    u32 tmp[NBUCK / 512];
    for (int i = t, q = 0; i < NBUCK; i += 512, ++q)
      tmp[q] = (i + off < NBUCK) ? hist[i + off] : 0u;
    __syncthreads();
    for (int i = t, q = 0; i < NBUCK; i += 512, ++q) hist[i] += tmp[q];
    __syncthreads();
  }
  for (int i = t; i < NBUCK; i += 512) {
    const u32 here = hist[i];
    const u32 nxt = (i + 1 < NBUCK) ? hist[i + 1] : 0u;
    if (here >= 64u && nxt < 64u) s_B = i;
  }
  __syncthreads();
  const int Bthr = s_B;   // hist dead from here; coll overlays it
  __syncthreads();
  if ((int)((mono0 >> 19) & 0xFFFu) >= Bthr) coll[atomicAdd(&s_cnt, 1)] = k0;
  if ((int)((mono1 >> 19) & 0xFFFu) >= Bthr) coll[atomicAdd(&s_cnt, 1)] = k1;
  __syncthreads();
  const int M = s_cnt;
  for (int i = t; i < M; i += 512) {
    const u64 ki = coll[i];
    int r = 0;
    for (int j2 = 0; j2 < M; ++j2) r += (coll[j2] > ki);
    if (r < 64)
      __hip_atomic_store(&rowtop[(size_t)w * 64 + r], ki,
                         __ATOMIC_RELAXED, __HIP_MEMORY_SCOPE_AGENT);
  }
  __syncthreads();
  if (t == 0)
    __hip_atomic_fetch_add(gcnt, 1, __ATOMIC_RELEASE, __HIP_MEMORY_SCOPE_AGENT);
  if (b != 0) return;

  // ================= top (block 0) =================
  if (t == 0) {
    const int target = 64 * (step + 1);
    while (__hip_atomic_load(gcnt, __ATOMIC_RELAXED, __HIP_MEMORY_SCOPE_AGENT) < target)
      __builtin_amdgcn_s_sleep(8);
    __builtin_amdgcn_fence(__ATOMIC_ACQUIRE, "agent");
  }
  __syncthreads();
  for (int i = t; i < NBUCK; i += 512) hist[i] = 0;
  if (t == 0) s_cnt = 0;
  __syncthreads();
  for (int i = t; i < W * 64; i += 512) {
    const u64 k = __hip_atomic_load(&rowtop[i], __ATOMIC_RELAXED, __HIP_MEMORY_SCOPE_AGENT);
    atomicAdd(&hist[(u32)(k >> 51) & 0xFFFu], 1u);
  }
  __syncthreads();
  for (int off = 1; off < NBUCK; off <<= 1) {
    u32 tmp[NBUCK / 512];
    for (int i = t, q = 0; i < NBUCK; i += 512, ++q)
      tmp[q] = (i + off < NBUCK) ? hist[i + off] : 0u;
    __syncthreads();
    for (int i = t, q = 0; i < NBUCK; i += 512, ++q) hist[i] += tmp[q];
    __syncthreads();
  }
  for (int i = t; i < NBUCK; i += 512) {
    const u32 here = hist[i];
    const u32 nxt = (i + 1 < NBUCK) ? hist[i + 1] : 0u;
    if (here >= 64u && nxt < 64u) s_B = i;
  }
  __syncthreads();
  const int Bthr2 = s_B;   // hist dead; coll (32 KB) overlays
  __syncthreads();
  for (int i = t; i < W * 64; i += 512) {
    const u64 k = __hip_atomic_load(&rowtop[i], __ATOMIC_RELAXED, __HIP_MEMORY_SCOPE_AGENT);
    if ((int)((k >> 51) & 0xFFFull) >= Bthr2) coll[atomicAdd(&s_cnt, 1)] = k;
  }
  __syncthreads();
  const int M2 = s_cnt;
  for (int i = t; i < M2; i += 512) {
    const u64 ki = coll[i];
    int r = 0;
    for (int j2 = 0; j2 < M2; ++j2) r += (coll[j2] > ki);
    if (r < 64) {
      const u32 flat = ~(u32)(ki & 0xFFFFFFFFull);
      const int p = (int)(flat >> 10);
      const int sl = (int)(flat & 1023u);
      const size_t cbase = (size_t)step * W * C + (size_t)p * C + sl;
      s_par[r] = p;
      s_rid[r] = cand_rel_ids[cbase];
      s_eid[r] = cand_ent_ids[cbase];
    }
  }
  __syncthreads();
  // stage next-step inputs: xin=[rel,ent,H[par]], cpb=C[par], curid=eid
  {
    const int wq = t >> 3, q = t & 7;
    const int rid = s_rid[wq], eid = s_eid[wq], par = s_par[wq];
    if (q == 0) curid[wq] = eid;
    const float4* rel4 = (const float4*)(rel_emb + (size_t)rid * E);
    const float4* ent4 = (const float4*)(ent_emb + (size_t)eid * E);
    const float4* h4   = (const float4*)(Hst + (size_t)par * E);
    const float4* c4   = (const float4*)(Cst + (size_t)par * E);
    float4* xi = (float4*)(xinb + (size_t)wq * 384);
    float4* cw = (float4*)(cpb + (size_t)wq * E);
#pragma unroll
    for (int ii = 0; ii < 4; ++ii) {
      const int idx = (q << 2) + ii;
      xi[idx]      = rel4[idx];
      xi[32 + idx] = ent4[idx];
      xi[64 + idx] = h4[idx];
      cw[idx]      = c4[idx];
    }
  }
}

// ---------------------------------------------------------------------------
extern "C" void kernel_launch(void* const* d_in, const int* in_sizes, int n_in,
                              void* d_out, int out_size, void* d_ws, size_t ws_size,
                              hipStream_t stream) {
  const float* ent_emb  = (const float*)d_in[0];
  const float* rel_emb  = (const float*)d_in[1];
  const float* relation = (const float*)d_in[2];
  const float* W1 = (const float*)d_in[3];
  const float* b1 = (const float*)d_in[4];
  const float* W2 = (const float*)d_in[5];
  const float* b2 = (const float*)d_in[6];
  const float* lstm_k = (const float*)d_in[7];
  const float* lstm_r = (const float*)d_in[8];
  const float* lstm_b = (const float*)d_in[9];
  const int* cr = (const int*)d_in[10];
  const int* ce = (const int*)d_in[11];
  const int* start_ent = (const int*)d_in[12];
  float* out = (float*)d_out;

  u64* rowtop = (u64*)d_ws;                                 // W*64 u64
  float* Hst   = (float*)(rowtop + (size_t)W * 64);         // W*E
  float* Cst   = Hst + (size_t)W * E;                       // W*E
  float* xinb  = Cst + (size_t)W * E;                       // W*384
  float* cpb   = xinb + (size_t)W * 384;                    // W*E
  float* featb = cpb + (size_t)W * E;                       // W*256
  float* scoresb = featb + (size_t)W * 256;                 // W*C
  int* curid = (int*)(scoresb + (size_t)W * C);             // W
  int* scnt  = curid + W;                                   // W
  int* gcnt  = scnt + W;                                    // 1

  for (int s = 0; s < S; ++s) {
    kFeat<<<W, 256, 0, stream>>>(s, ent_emb, relation, W1, b1, W2, b2,
                                 lstm_k, lstm_r, lstm_b, start_ent,
                                 xinb, cpb, curid, Hst, Cst, featb, scnt, gcnt);
    kSP<<<512, 512, 0, stream>>>(s, (s == S - 1) ? 1 : 0,
                                 ent_emb, rel_emb, relation, cr, ce,
                                 featb, scoresb, out, rowtop,
                                 Hst, Cst, xinb, cpb, curid, scnt, gcnt);
  }
}

// Round 8
// 570.950 us; speedup vs baseline: 1.3688x; 1.3688x over previous
//
#include <hip/hip_runtime.h>
#include <stdint.h>

#define E 128
#define W 64
#define C 1024
#define S 8
#define NBUCK 4096

typedef unsigned long long u64;
typedef unsigned int u32;

__device__ __forceinline__ float sigm(float x) { return 1.0f / (1.0f + expf(-x)); }

// ---------------------------------------------------------------------------
// kFeat: rank-w + gather + LSTM + MLP chain. grid = 64 x 384.
//   step>0: each block ranks rowtop (4096 keys) and takes rank w as its
//   (parent, sel); gathers inputs directly. H/C double-buffered across steps.
//   GEMVs: float4 weight loads, k-sliced, LDS combine.
// ---------------------------------------------------------------------------
__global__ __launch_bounds__(384) void kFeat(
    int step,
    const float* __restrict__ ent_emb, const float* __restrict__ rel_emb,
    const float* __restrict__ relation,
    const float* __restrict__ W1, const float* __restrict__ b1,
    const float* __restrict__ W2, const float* __restrict__ b2,
    const float* __restrict__ lstm_k, const float* __restrict__ lstm_r,
    const float* __restrict__ lstm_b,
    const int* __restrict__ cand_rel_ids, const int* __restrict__ cand_ent_ids,
    const int* __restrict__ start_ent,
    const u64* __restrict__ rowtop,
    float* __restrict__ Hst, float* __restrict__ Cst,   // each [2][W][E]
    float* __restrict__ featb)                           // [W][256]
{
  const int w = blockIdx.x, t = threadIdx.x;
  __shared__ __align__(16) float xin[384];
  __shared__ __align__(16) float xcat[384];
  __shared__ __align__(16) float hmid[384];
  __shared__ __align__(16) float4 zacc[384];
  __shared__ __align__(16) float z[512];
  __shared__ float hnew[128];
  __shared__ __align__(16) unsigned char arena[32768];
  u32* hist = (u32*)arena;     // 16 KB (rank phase)
  u64* coll = (u64*)arena;     // 32 KB overlay (after threshold known)
  __shared__ int s_par, s_rid, s_eid;
  __shared__ int s_cnt, s_B;

  float* Hn = Hst + (size_t)(step & 1) * W * E;
  float* Cn = Cst + (size_t)(step & 1) * W * E;
  const float* Hp = Hst + (size_t)((step + 1) & 1) * W * E;
  const float* Cp = Cst + (size_t)((step + 1) & 1) * W * E;

  int cur;
  if (step == 0) {
    if (t < 128) {
      hnew[t] = 0.f;
      Hn[w * E + t] = 0.f;
      Cn[w * E + t] = 0.f;
    }
    cur = start_ent[w];
  } else {
    // ---- rank phase: global top-64 over rowtop, keep rank w -------------
    for (int i = t; i < NBUCK; i += 384) hist[i] = 0;
    if (t == 0) s_cnt = 0;
    __syncthreads();
    for (int i = t; i < W * 64; i += 384) {
      const u64 k = rowtop[i];
      atomicAdd(&hist[(u32)(k >> 51) & 0xFFFu], 1u);
    }
    __syncthreads();
    for (int off = 1; off < NBUCK; off <<= 1) {
      u32 tmp[11];
      for (int i = t, q = 0; i < NBUCK; i += 384, ++q)
        tmp[q] = (i + off < NBUCK) ? hist[i + off] : 0u;
      __syncthreads();
      for (int i = t, q = 0; i < NBUCK; i += 384, ++q) hist[i] += tmp[q];
      __syncthreads();
    }
    for (int i = t; i < NBUCK; i += 384) {
      const u32 here = hist[i];
      const u32 nxt = (i + 1 < NBUCK) ? hist[i + 1] : 0u;
      if (here >= 64u && nxt < 64u) s_B = i;
    }
    __syncthreads();
    const int Bthr = s_B;
    __syncthreads();            // hist dead; coll overlays arena
    for (int i = t; i < W * 64; i += 384) {
      const u64 k = rowtop[i];
      if ((int)((k >> 51) & 0xFFFull) >= Bthr) coll[atomicAdd(&s_cnt, 1)] = k;
    }
    __syncthreads();
    const int M = s_cnt;
    for (int i = t; i < M; i += 384) {
      const u64 ki = coll[i];
      int r = 0;
      for (int j = 0; j < M; ++j) r += (coll[j] > ki);
      if (r == w) {
        const u32 flat = ~(u32)(ki & 0xFFFFFFFFull);
        const int p = (int)(flat >> 10);
        const int sl = (int)(flat & 1023u);
        const size_t cbase = (size_t)(step - 1) * W * C + (size_t)p * C + sl;
        s_par = p;
        s_rid = cand_rel_ids[cbase];
        s_eid = cand_ent_ids[cbase];
      }
    }
    __syncthreads();
    const int par = s_par, rid = s_rid, eid = s_eid;
    cur = eid;
    // ---- gather xin = [rel_emb[rid], ent_emb[eid], Hp[par]] -------------
    {
      float v;
      if (t < 128) v = rel_emb[(size_t)rid * E + t];
      else if (t < 256) v = ent_emb[(size_t)eid * E + (t - 128)];
      else v = Hp[(size_t)par * E + (t - 256)];
      xin[t] = v;
    }
    __syncthreads();
    // ---- z-GEMV: 512 outputs, (jg<128) x (ks<3) ------------------------
    {
      const int ks = t >> 7, jg = t & 127, j0 = jg << 2;
      float4 acc = make_float4(0.f, 0.f, 0.f, 0.f);
      if (ks < 2) {
        const int k0 = ks << 7;
#pragma unroll 4
        for (int kk = 0; kk < 128; ++kk) {
          const int k = k0 + kk;
          const float4 wt = *(const float4*)(lstm_k + (size_t)k * 512 + j0);
          const float xk = xin[k];
          acc.x += xk * wt.x; acc.y += xk * wt.y;
          acc.z += xk * wt.z; acc.w += xk * wt.w;
        }
      } else {
#pragma unroll 4
        for (int kk = 0; kk < 128; ++kk) {
          const float4 wt = *(const float4*)(lstm_r + (size_t)kk * 512 + j0);
          const float xk = xin[256 + kk];
          acc.x += xk * wt.x; acc.y += xk * wt.y;
          acc.z += xk * wt.z; acc.w += xk * wt.w;
        }
      }
      zacc[t] = acc;
    }
    __syncthreads();
    if (t < 128) {
      const float4 a = zacc[t], b = zacc[128 + t], c = zacc[256 + t];
      const float4 bb = *(const float4*)(lstm_b + (t << 2));
      float4 zv;
      zv.x = a.x + b.x + c.x + bb.x;
      zv.y = a.y + b.y + c.y + bb.y;
      zv.z = a.z + b.z + c.z + bb.z;
      zv.w = a.w + b.w + c.w + bb.w;
      ((float4*)z)[t] = zv;
    }
    __syncthreads();
    if (t < 128) {
      const float zi = z[t], zf = z[128 + t], zg = z[256 + t], zo = z[384 + t];
      const float cp = Cp[(size_t)par * E + t];
      const float cn = sigm(zf) * cp + sigm(zi) * tanhf(zg);
      const float hn = sigm(zo) * tanhf(cn);
      hnew[t] = hn;
      Hn[w * E + t] = hn;
      Cn[w * E + t] = cn;
    }
  }
  __syncthreads();

  // ---- xcat = [ent_emb[cur], hnew, relation] -----------------------------
  {
    float v;
    if (t < 128) v = ent_emb[(size_t)cur * E + t];
    else if (t < 256) v = hnew[t - 128];
    else v = relation[t - 256];
    xcat[t] = v;
  }
  __syncthreads();

  // ---- MLP1: 384 outputs, (jg<96) x (ks<4) -------------------------------
  {
    const int jg = t % 96, ks = t / 96, j0 = jg << 2, k0 = ks * 96;
    float4 acc = make_float4(0.f, 0.f, 0.f, 0.f);
#pragma unroll 4
    for (int kk = 0; kk < 96; ++kk) {
      const int k = k0 + kk;
      const float4 wt = *(const float4*)(W1 + (size_t)k * 384 + j0);
      const float xk = xcat[k];
      acc.x += xk * wt.x; acc.y += xk * wt.y;
      acc.z += xk * wt.z; acc.w += xk * wt.w;
    }
    zacc[t] = acc;
  }
  __syncthreads();
  if (t < 96) {
    const float4 a = zacc[t], b = zacc[96 + t], c = zacc[192 + t], d = zacc[288 + t];
    const float4 bb = *(const float4*)(b1 + (t << 2));
    float4 hv;
    hv.x = fmaxf(a.x + b.x + c.x + d.x + bb.x, 0.f);
    hv.y = fmaxf(a.y + b.y + c.y + d.y + bb.y, 0.f);
    hv.z = fmaxf(a.z + b.z + c.z + d.z + bb.z, 0.f);
    hv.w = fmaxf(a.w + b.w + c.w + d.w + bb.w, 0.f);
    ((float4*)hmid)[t] = hv;
  }
  __syncthreads();

  // ---- MLP2: 256 outputs, (jg<64) x (ks<6) -------------------------------
  {
    const int jg = t & 63, ks = t >> 6, j0 = jg << 2, k0 = ks << 6;
    float4 acc = make_float4(0.f, 0.f, 0.f, 0.f);
#pragma unroll 4
    for (int kk = 0; kk < 64; ++kk) {
      const int k = k0 + kk;
      const float4 wt = *(const float4*)(W2 + (size_t)k * 256 + j0);
      const float xk = hmid[k];
      acc.x += xk * wt.x; acc.y += xk * wt.y;
      acc.z += xk * wt.z; acc.w += xk * wt.w;
    }
    zacc[t] = acc;
  }
  __syncthreads();
  if (t < 64) {
    float4 acc = zacc[t];
#pragma unroll
    for (int sl = 1; sl < 6; ++sl) {
      const float4 a = zacc[sl * 64 + t];
      acc.x += a.x; acc.y += a.y; acc.z += a.z; acc.w += a.w;
    }
    const float4 bb = *(const float4*)(b2 + (t << 2));
    float4 fv;
    fv.x = fmaxf(acc.x + bb.x, 0.f);
    fv.y = fmaxf(acc.y + bb.y, 0.f);
    fv.z = fmaxf(acc.z + bb.z, 0.f);
    fv.w = fmaxf(acc.w + bb.w, 0.f);
    ((float4*)(featb + (size_t)w * 256))[t] = fv;
  }
}

// ---------------------------------------------------------------------------
// kScore: gather-bound scoring, 4 threads/candidate. grid = 512 x 512.
// ---------------------------------------------------------------------------
__global__ __launch_bounds__(512) void kScore(
    int step,
    const float* __restrict__ ent_emb, const float* __restrict__ rel_emb,
    const int* __restrict__ cand_rel_ids, const int* __restrict__ cand_ent_ids,
    const float* __restrict__ featb, float* __restrict__ scoresb)
{
  const int b = blockIdx.x, tid = threadIdx.x;
  const int w = b >> 3, c0 = (b & 7) << 7;
  __shared__ __align__(16) float featl[256];
  __shared__ int srid[128], seid[128];

  const size_t idbase = (size_t)step * W * C + (size_t)w * C + c0;
  if (tid < 256) featl[tid] = featb[(size_t)w * 256 + tid];
  else if (tid < 384) srid[tid - 256] = cand_rel_ids[idbase + (tid - 256)];
  else seid[tid - 384] = cand_ent_ids[idbase + (tid - 384)];
  __syncthreads();

  const int cl = tid >> 2, j = tid & 3;
  const float4* rp = (const float4*)(rel_emb + (size_t)srid[cl] * E);
  const float4* ep = (const float4*)(ent_emb + (size_t)seid[cl] * E);
  const float4* f4 = (const float4*)featl;
  float ax = 0.f, ay = 0.f, az = 0.f, aw = 0.f;
#pragma unroll
  for (int i = 0; i < 8; ++i) {
    const float4 r = rp[j + 4 * i], f = f4[j + 4 * i];
    ax += r.x * f.x; ay += r.y * f.y; az += r.z * f.z; aw += r.w * f.w;
  }
#pragma unroll
  for (int i = 0; i < 8; ++i) {
    const float4 e = ep[j + 4 * i], f = f4[32 + j + 4 * i];
    ax += e.x * f.x; ay += e.y * f.y; az += e.z * f.z; aw += e.w * f.w;
  }
  float acc = (ax + ay) + (az + aw);
  acc += __shfl_xor(acc, 1, 64);
  acc += __shfl_xor(acc, 2, 64);
  if (j == 0) scoresb[(size_t)w * C + c0 + cl] = acc;
}

// ---------------------------------------------------------------------------
// kProb: softmax + probs write + per-row top-64. grid = 64 x 1024.
// ---------------------------------------------------------------------------
__global__ __launch_bounds__(1024) void kProb(
    int step, int last, const float* __restrict__ scoresb,
    float* __restrict__ out, u64* __restrict__ rowtop)
{
  const int w = blockIdx.x, tid = threadIdx.x;
  __shared__ float sred[32];
  __shared__ u32 hist[NBUCK];
  __shared__ u64 coll[C];
  __shared__ int s_cnt, s_B;

  const float score = scoresb[(size_t)w * C + tid];

  float v = score;
#pragma unroll
  for (int m = 32; m; m >>= 1) v = fmaxf(v, __shfl_xor(v, m, 64));
  if ((tid & 63) == 0) sred[tid >> 6] = v;
  __syncthreads();
  if (tid == 0) {
    float mm = sred[0];
#pragma unroll
    for (int i = 1; i < 16; ++i) mm = fmaxf(mm, sred[i]);
    sred[16] = mm;
  }
  __syncthreads();
  const float m = sred[16];
  const float pexp = expf(score - m);
  v = pexp;
#pragma unroll
  for (int mm2 = 32; mm2; mm2 >>= 1) v += __shfl_xor(v, mm2, 64);
  if ((tid & 63) == 0) sred[tid >> 6] = v;
  __syncthreads();
  if (tid == 0) {
    float ss = sred[0];
#pragma unroll
    for (int i = 1; i < 16; ++i) ss += sred[i];
    sred[17] = 1.f / ss;
  }
  __syncthreads();
  const float prob = pexp * sred[17];
  out[(size_t)step * W * C + (size_t)w * C + tid] = prob;
  if (last) return;

  for (int i = tid; i < NBUCK; i += 1024) hist[i] = 0;
  if (tid == 0) s_cnt = 0;
  __syncthreads();
  const u32 mono = __float_as_uint(prob) | 0x80000000u;
  const u64 key = ((u64)mono << 32) | (u32)~(u32)(w * C + tid);
  atomicAdd(&hist[(mono >> 19) & 0xFFFu], 1u);
  __syncthreads();
  for (int off = 1; off < NBUCK; off <<= 1) {
    u32 tmp[NBUCK / 1024];
    for (int i = tid, q = 0; i < NBUCK; i += 1024, ++q)
      tmp[q] = (i + off < NBUCK) ? hist[i + off] : 0u;
    __syncthreads();
    for (int i = tid, q = 0; i < NBUCK; i += 1024, ++q) hist[i] += tmp[q];
    __syncthreads();
  }
  for (int i = tid; i < NBUCK; i += 1024) {
    const u32 here = hist[i];
    const u32 nxt = (i + 1 < NBUCK) ? hist[i + 1] : 0u;
    if (here >= 64u && nxt < 64u) s_B = i;
  }
  __syncthreads();
  if ((int)((mono >> 19) & 0xFFFu) >= s_B) {
    const int q = atomicAdd(&s_cnt, 1);
    coll[q] = key;
  }
  __syncthreads();
  const int M = s_cnt;
  for (int i = tid; i < M; i += 1024) {
    const u64 ki = coll[i];
    int r = 0;
    for (int j = 0; j < M; ++j) r += (coll[j] > ki);
    if (r < 64) rowtop[(size_t)w * 64 + r] = ki;
  }
}

// ---------------------------------------------------------------------------
extern "C" void kernel_launch(void* const* d_in, const int* in_sizes, int n_in,
                              void* d_out, int out_size, void* d_ws, size_t ws_size,
                              hipStream_t stream) {
  const float* ent_emb  = (const float*)d_in[0];
  const float* rel_emb  = (const float*)d_in[1];
  const float* relation = (const float*)d_in[2];
  const float* W1 = (const float*)d_in[3];
  const float* b1 = (const float*)d_in[4];
  const float* W2 = (const float*)d_in[5];
  const float* b2 = (const float*)d_in[6];
  const float* lstm_k = (const float*)d_in[7];
  const float* lstm_r = (const float*)d_in[8];
  const float* lstm_b = (const float*)d_in[9];
  const int* cr = (const int*)d_in[10];
  const int* ce = (const int*)d_in[11];
  const int* start_ent = (const int*)d_in[12];
  float* out = (float*)d_out;

  u64* rowtop = (u64*)d_ws;                                 // W*64 u64
  float* Hst   = (float*)(rowtop + (size_t)W * 64);         // 2*W*E
  float* Cst   = Hst + (size_t)2 * W * E;                   // 2*W*E
  float* featb = Cst + (size_t)2 * W * E;                   // W*256
  float* scoresb = featb + (size_t)W * 256;                 // W*C

  for (int s = 0; s < S; ++s) {
    kFeat<<<W, 384, 0, stream>>>(s, ent_emb, rel_emb, relation, W1, b1, W2, b2,
                                 lstm_k, lstm_r, lstm_b, cr, ce, start_ent,
                                 rowtop, Hst, Cst, featb);
    kScore<<<512, 512, 0, stream>>>(s, ent_emb, rel_emb, cr, ce, featb, scoresb);
    kProb<<<W, 1024, 0, stream>>>(s, (s == S - 1) ? 1 : 0, scoresb, out, rowtop);
  }
}

// Round 9
// 516.970 us; speedup vs baseline: 1.5117x; 1.1044x over previous
//
#include <hip/hip_runtime.h>
#include <stdint.h>

#define E 128
#define W 64
#define C 1024
#define S 8
#define NBUCK 4096

typedef unsigned long long u64;
typedef unsigned int u32;

__device__ __forceinline__ float sigm(float x) { return 1.0f / (1.0f + expf(-x)); }

// Wave-level suffix-scan threshold finder over hist[4096] (counts -> suffix in
// place). 1024 threads, 4 buckets/thread. 3 barriers. Returns bucket B such
// that #keys in buckets >= B is >= 64 and #keys in buckets > B is < 64.
__device__ __forceinline__ int suffix_threshold(u32* hist, u32* wtot, int* s_B,
                                                int t, int lane, int wid) {
  const int b0 = t << 2;
  const u32 v0 = hist[b0], v1 = hist[b0 + 1], v2 = hist[b0 + 2], v3 = hist[b0 + 3];
  const u32 s3 = v3, s2 = v2 + s3, s1 = v1 + s2, s0 = v0 + s1;
  u32 incl = s0;
#pragma unroll
  for (int off = 1; off < 64; off <<= 1) {
    const u32 n = __shfl_down(incl, off, 64);
    if (lane + off < 64) incl += n;
  }
  if (lane == 0) wtot[wid] = incl;     // wave total
  __syncthreads();
  u32 wsuf = 0;
  for (int i = wid + 1; i < 16; ++i) wsuf += wtot[i];
  const u32 above = wsuf + (incl - s0);  // keys strictly after my 4 buckets
  hist[b0]     = above + s0;
  hist[b0 + 1] = above + s1;
  hist[b0 + 2] = above + s2;
  hist[b0 + 3] = above + s3;
  __syncthreads();
#pragma unroll
  for (int j = 0; j < 4; ++j) {
    const int b = b0 + j;
    const u32 here = hist[b];
    const u32 nxt = (b + 1 < NBUCK) ? hist[b + 1] : 0u;
    if (here >= 64u && nxt < 64u) *s_B = b;
  }
  __syncthreads();
  return *s_B;
}

// ---------------------------------------------------------------------------
// kStep: ONE kernel per step. grid = 64 (beam) x 1024.
//  R: redundant global top-64 rank over rowtop -> (parent, rid, eid) for beam w
//  G: gather xin=[rel,ent,h_par], xcat ent part
//  Z: lstm z GEMM (k-sliced f4) + gates -> H,C,hnew
//  M1/M2: MLP (rconst trick: relation@W1 precomputed at step 0)
//  S: 1 cand/thread scoring (HBM gather)
//  SM: in-register softmax -> out
//  T: per-row top-64 -> rowtop
// ---------------------------------------------------------------------------
__global__ __launch_bounds__(1024) void kStep(
    int step, int last,
    const float* __restrict__ ent_emb, const float* __restrict__ rel_emb,
    const float* __restrict__ relation,
    const float* __restrict__ W1, const float* __restrict__ b1,
    const float* __restrict__ W2, const float* __restrict__ b2,
    const float* __restrict__ lstm_k, const float* __restrict__ lstm_r,
    const float* __restrict__ lstm_b,
    const int* __restrict__ cand_rel_ids, const int* __restrict__ cand_ent_ids,
    const int* __restrict__ start_ent,
    float* __restrict__ Hst, float* __restrict__ Cst,   // each [2][W][E]
    float* __restrict__ rconstb,                         // [384]
    u64* __restrict__ rowtop,                            // [W][64]
    float* __restrict__ out)
{
  const int w = blockIdx.x, t = threadIdx.x;
  const int lane = t & 63, wid = t >> 6;
  __shared__ __align__(16) float xin[384];
  __shared__ __align__(16) float xcat2[256];   // [ent_emb[cur], hnew]
  __shared__ __align__(16) float z[512];       // lstm z; rconst at step 0
  __shared__ __align__(16) float hmid[384];
  __shared__ __align__(16) float featl[256];
  __shared__ float sred[16];
  __shared__ float s_m, s_inv;
  __shared__ u32 wtot[16];
  __shared__ int s_par, s_rid, s_eid, s_cnt, s_B;
  __shared__ __align__(16) unsigned char arena[32768];
  u32* hist = (u32*)arena;
  u64* coll = (u64*)arena;
  float4* zacc = (float4*)arena;

  float* Hn = Hst + (size_t)(step & 1) * W * E;
  float* Cn = Cst + (size_t)(step & 1) * W * E;
  const float* Hp = Hst + (size_t)((step + 1) & 1) * W * E;
  const float* Cp = Cst + (size_t)((step + 1) & 1) * W * E;

  // prefetch this thread's candidate ids (used in phase S)
  const size_t sbase = (size_t)step * W * C + (size_t)w * C + t;
  const int d_rid = cand_rel_ids[sbase];
  const int d_eid = cand_ent_ids[sbase];

  if (step == 0) {
    // ---- init + rconst = relation @ W1[256:384,:] -------------------------
    const int cur = start_ent[w];
    if (t < 128) {
      xcat2[t] = ent_emb[(size_t)cur * E + t];
      xcat2[128 + t] = 0.f;
      Hn[w * E + t] = 0.f;
      Cn[w * E + t] = 0.f;
    }
    if (t < 384) {
      const int jg = t % 96, ks = t / 96;       // 4 slices x 32 rows
      const int j0 = jg << 2, k0 = ks << 5;
      float4 acc = make_float4(0.f, 0.f, 0.f, 0.f);
#pragma unroll 8
      for (int kk = 0; kk < 32; ++kk) {
        const int k = k0 + kk;
        const float4 wt = *(const float4*)(W1 + (size_t)(256 + k) * 384 + j0);
        const float xk = relation[k];
        acc.x += xk * wt.x; acc.y += xk * wt.y;
        acc.z += xk * wt.z; acc.w += xk * wt.w;
      }
      zacc[t] = acc;
    }
    __syncthreads();
    if (t < 96) {
      float4 a = zacc[t];
#pragma unroll
      for (int sl = 1; sl < 4; ++sl) {
        const float4 bq = zacc[sl * 96 + t];
        a.x += bq.x; a.y += bq.y; a.z += bq.z; a.w += bq.w;
      }
      ((float4*)z)[t] = a;                       // rconst in LDS (z is free)
      *(float4*)(rconstb + (t << 2)) = a;        // persist for later steps
    }
    __syncthreads();
  } else {
    // ---- R: rank rowtop, keep rank w --------------------------------------
    if (t == 0) s_cnt = 0;
    ((uint4*)hist)[t] = make_uint4(0u, 0u, 0u, 0u);
    __syncthreads();
    u64 myk[4];
#pragma unroll
    for (int j = 0; j < 4; ++j) {
      myk[j] = rowtop[t + (j << 10)];
      atomicAdd(&hist[(u32)(myk[j] >> 51) & 0xFFFu], 1u);
    }
    __syncthreads();
    const int B = suffix_threshold(hist, wtot, &s_B, t, lane, wid);
#pragma unroll
    for (int j = 0; j < 4; ++j)
      if ((int)((myk[j] >> 51) & 0xFFFull) >= B) coll[atomicAdd(&s_cnt, 1)] = myk[j];
    __syncthreads();
    const int M = s_cnt;
    for (int i = t; i < M; i += 1024) {
      const u64 ki = coll[i];
      int r = 0;
      for (int j = 0; j < M; ++j) r += (coll[j] > ki);
      if (r == w) {
        const u32 flat = ~(u32)(ki & 0xFFFFFFFFull);
        const int p = (int)(flat >> 10);
        const int sl = (int)(flat & 1023u);
        const size_t cbase = (size_t)(step - 1) * W * C + (size_t)p * C + sl;
        s_par = p;
        s_rid = cand_rel_ids[cbase];
        s_eid = cand_ent_ids[cbase];
      }
    }
    __syncthreads();
    const int par = s_par, rid = s_rid, eid = s_eid;
    // ---- G: gather --------------------------------------------------------
    if (t < 384) {
      float v;
      if (t < 128) v = rel_emb[(size_t)rid * E + t];
      else if (t < 256) v = ent_emb[(size_t)eid * E + (t - 128)];
      else v = Hp[(size_t)par * E + (t - 256)];
      xin[t] = v;
    } else if (t < 512) {
      xcat2[t - 384] = ent_emb[(size_t)eid * E + (t - 384)];
    }
    __syncthreads();
    // ---- Z: z = xin @ [K;R] + b, 8 k-slices x 48 rows, f4 cols ------------
    {
      const int ks = t >> 7, jg = t & 127;
      const int j0 = jg << 2, k0 = ks * 48;
      float4 acc = make_float4(0.f, 0.f, 0.f, 0.f);
#pragma unroll 8
      for (int kk = 0; kk < 48; ++kk) {
        const int k = k0 + kk;
        const float* Wp = (k < 256) ? (lstm_k + (size_t)k * 512 + j0)
                                    : (lstm_r + (size_t)(k - 256) * 512 + j0);
        const float4 wt = *(const float4*)Wp;
        const float xk = xin[k];
        acc.x += xk * wt.x; acc.y += xk * wt.y;
        acc.z += xk * wt.z; acc.w += xk * wt.w;
      }
      zacc[t] = acc;
    }
    __syncthreads();
    if (t < 128) {
      float4 a = zacc[t];
#pragma unroll
      for (int sl = 1; sl < 8; ++sl) {
        const float4 bq = zacc[sl * 128 + t];
        a.x += bq.x; a.y += bq.y; a.z += bq.z; a.w += bq.w;
      }
      const float4 bb = *(const float4*)(lstm_b + (t << 2));
      a.x += bb.x; a.y += bb.y; a.z += bb.z; a.w += bb.w;
      ((float4*)z)[t] = a;
    }
    __syncthreads();
    if (t < 128) {
      const float zi = z[t], zf = z[128 + t], zg = z[256 + t], zo = z[384 + t];
      const float cp = Cp[(size_t)par * E + t];
      const float cn = sigm(zf) * cp + sigm(zi) * tanhf(zg);
      const float hn = sigm(zo) * tanhf(cn);
      xcat2[128 + t] = hn;
      Hn[w * E + t] = hn;
      Cn[w * E + t] = cn;
    }
    __syncthreads();
  }

  // ---- M1: hmid = relu(xcat2 @ W1[0:256,:] + rconst + b1) ------------------
  if (t < 768) {
    const int jg = t % 96, ks = t / 96;          // 8 slices x 32 rows
    const int j0 = jg << 2, k0 = ks << 5;
    float4 acc = make_float4(0.f, 0.f, 0.f, 0.f);
#pragma unroll 8
    for (int kk = 0; kk < 32; ++kk) {
      const int k = k0 + kk;
      const float4 wt = *(const float4*)(W1 + (size_t)k * 384 + j0);
      const float xk = xcat2[k];
      acc.x += xk * wt.x; acc.y += xk * wt.y;
      acc.z += xk * wt.z; acc.w += xk * wt.w;
    }
    zacc[t] = acc;
  }
  __syncthreads();
  if (t < 96) {
    float4 a = zacc[t];
#pragma unroll
    for (int sl = 1; sl < 8; ++sl) {
      const float4 bq = zacc[sl * 96 + t];
      a.x += bq.x; a.y += bq.y; a.z += bq.z; a.w += bq.w;
    }
    const float4 rc = (step == 0) ? ((const float4*)z)[t]
                                  : *(const float4*)(rconstb + (t << 2));
    const float4 bb = *(const float4*)(b1 + (t << 2));
    float4 hv;
    hv.x = fmaxf(a.x + rc.x + bb.x, 0.f);
    hv.y = fmaxf(a.y + rc.y + bb.y, 0.f);
    hv.z = fmaxf(a.z + rc.z + bb.z, 0.f);
    hv.w = fmaxf(a.w + rc.w + bb.w, 0.f);
    ((float4*)hmid)[t] = hv;
  }
  __syncthreads();

  // ---- M2: feat = relu(hmid @ W2 + b2), 16 k-slices x 24 rows --------------
  {
    const int jg = t & 63, ks = t >> 6;
    const int j0 = jg << 2, k0 = ks * 24;
    float4 acc = make_float4(0.f, 0.f, 0.f, 0.f);
#pragma unroll 8
    for (int kk = 0; kk < 24; ++kk) {
      const int k = k0 + kk;
      const float4 wt = *(const float4*)(W2 + (size_t)k * 256 + j0);
      const float xk = hmid[k];
      acc.x += xk * wt.x; acc.y += xk * wt.y;
      acc.z += xk * wt.z; acc.w += xk * wt.w;
    }
    zacc[t] = acc;
  }
  __syncthreads();
  if (t < 64) {
    float4 a = zacc[t];
#pragma unroll
    for (int sl = 1; sl < 16; ++sl) {
      const float4 bq = zacc[sl * 64 + t];
      a.x += bq.x; a.y += bq.y; a.z += bq.z; a.w += bq.w;
    }
    const float4 bb = *(const float4*)(b2 + (t << 2));
    float4 fv;
    fv.x = fmaxf(a.x + bb.x, 0.f);
    fv.y = fmaxf(a.y + bb.y, 0.f);
    fv.z = fmaxf(a.z + bb.z, 0.f);
    fv.w = fmaxf(a.w + bb.w, 0.f);
    ((float4*)featl)[t] = fv;
  }
  __syncthreads();

  // ---- S: score candidate t ------------------------------------------------
  float score;
  {
    const float4* rp = (const float4*)(rel_emb + (size_t)d_rid * E);
    const float4* ep = (const float4*)(ent_emb + (size_t)d_eid * E);
    const float4* f4 = (const float4*)featl;
    float ax = 0.f, ay = 0.f, az = 0.f, aw = 0.f;
#pragma unroll
    for (int i = 0; i < 32; ++i) {
      const float4 r = rp[i], f = f4[i];
      ax += r.x * f.x; ay += r.y * f.y; az += r.z * f.z; aw += r.w * f.w;
    }
#pragma unroll
    for (int i = 0; i < 32; ++i) {
      const float4 e = ep[i], f = f4[32 + i];
      ax += e.x * f.x; ay += e.y * f.y; az += e.z * f.z; aw += e.w * f.w;
    }
    score = (ax + ay) + (az + aw);
  }

  // ---- SM: softmax ---------------------------------------------------------
  float v = score;
#pragma unroll
  for (int d = 32; d; d >>= 1) v = fmaxf(v, __shfl_xor(v, d, 64));
  if (lane == 0) sred[wid] = v;
  __syncthreads();
  if (t == 0) {
    float mm = sred[0];
#pragma unroll
    for (int i = 1; i < 16; ++i) mm = fmaxf(mm, sred[i]);
    s_m = mm;
  }
  __syncthreads();
  const float pexp = expf(score - s_m);
  v = pexp;
#pragma unroll
  for (int d = 32; d; d >>= 1) v += __shfl_xor(v, d, 64);
  if (lane == 0) sred[wid] = v;
  __syncthreads();
  if (t == 0) {
    float ss = sred[0];
#pragma unroll
    for (int i = 1; i < 16; ++i) ss += sred[i];
    s_inv = 1.f / ss;
  }
  __syncthreads();
  const float prob = pexp * s_inv;
  out[(size_t)step * W * C + (size_t)w * C + t] = prob;

  // ---- T: per-row top-64 ---------------------------------------------------
  if (!last) {
    ((uint4*)hist)[t] = make_uint4(0u, 0u, 0u, 0u);
    if (t == 0) s_cnt = 0;
    __syncthreads();
    const u32 mono = __float_as_uint(prob) | 0x80000000u;
    const u64 key = ((u64)mono << 32) | (u32)~(u32)(w * C + t);
    atomicAdd(&hist[(mono >> 19) & 0xFFFu], 1u);
    __syncthreads();
    const int B = suffix_threshold(hist, wtot, &s_B, t, lane, wid);
    if ((int)((mono >> 19) & 0xFFFu) >= B) coll[atomicAdd(&s_cnt, 1)] = key;
    __syncthreads();
    const int M = s_cnt;
    for (int i = t; i < M; i += 1024) {
      const u64 ki = coll[i];
      int r = 0;
      for (int j = 0; j < M; ++j) r += (coll[j] > ki);
      if (r < 64) rowtop[(size_t)w * 64 + r] = ki;
    }
  }
}

// ---------------------------------------------------------------------------
extern "C" void kernel_launch(void* const* d_in, const int* in_sizes, int n_in,
                              void* d_out, int out_size, void* d_ws, size_t ws_size,
                              hipStream_t stream) {
  const float* ent_emb  = (const float*)d_in[0];
  const float* rel_emb  = (const float*)d_in[1];
  const float* relation = (const float*)d_in[2];
  const float* W1 = (const float*)d_in[3];
  const float* b1 = (const float*)d_in[4];
  const float* W2 = (const float*)d_in[5];
  const float* b2 = (const float*)d_in[6];
  const float* lstm_k = (const float*)d_in[7];
  const float* lstm_r = (const float*)d_in[8];
  const float* lstm_b = (const float*)d_in[9];
  const int* cr = (const int*)d_in[10];
  const int* ce = (const int*)d_in[11];
  const int* start_ent = (const int*)d_in[12];
  float* out = (float*)d_out;

  u64* rowtop = (u64*)d_ws;                                 // W*64 u64
  float* Hst = (float*)(rowtop + (size_t)W * 64);           // 2*W*E
  float* Cst = Hst + (size_t)2 * W * E;                     // 2*W*E
  float* rconstb = Cst + (size_t)2 * W * E;                 // 384

  for (int s = 0; s < S; ++s) {
    kStep<<<W, 1024, 0, stream>>>(s, (s == S - 1) ? 1 : 0,
                                  ent_emb, rel_emb, relation, W1, b1, W2, b2,
                                  lstm_k, lstm_r, lstm_b, cr, ce, start_ent,
                                  Hst, Cst, rconstb, rowtop, out);
  }
}